// Round 4
// baseline (1539.162 us; speedup 1.0000x reference)
//
#include <hip/hip_runtime.h>
#include <math.h>

// SparseDiffAttn: B=1,H=12,N=2048,D=128, BM=64, top-k=192, static window [c-153,c+153),
// random keys via modern-JAX randint under jax_threefry_partitionable=True:
//   k1 = tf((0,1),(0,0)), k2 = tf((0,1),(0,1))        [fold-like split]
//   bits(k,i) = b1^b2 with (b1,b2) = tf(k,(0,i))      [partitionable random_bits, 32-bit]
//   offset = ((hi%100)*96 + lo%100) % 100; rnd <=> offset==0
constexpr int Hh   = 12;
constexpr int Nn   = 2048;
constexpr int Dd   = 128;
constexpr int BMq  = 64;
constexpr int QGg  = 32;            // Nn/BMq
constexpr int KSEL = 192;           // 64 * round(0.1*2048/64)
constexpr int CK   = 32;            // key chunk
constexpr float SCALE = 0.08838834764831845f;  // 1/sqrt(128)

// persistent scratch (fully rewritten every launch before any read)
__device__ float          g_bs [Hh*QGg*Nn];
__device__ unsigned short g_sel[Hh*QGg*Nn];
__device__ int            g_cnt[Hh*QGg];

__device__ __forceinline__ unsigned int rotl32(unsigned int x, int n){
  return (x << n) | (x >> (32 - n));
}

// threefry2x32, 20 rounds, arbitrary key
__device__ __forceinline__ void tf2x32(unsigned int k0, unsigned int k1,
                                       unsigned int x0, unsigned int x1,
                                       unsigned int &o0, unsigned int &o1){
  const unsigned int ks2 = 0x1BD11BDAu ^ k0 ^ k1;
  x0 += k0; x1 += k1;
  x0 += x1; x1 = rotl32(x1,13); x1 ^= x0;
  x0 += x1; x1 = rotl32(x1,15); x1 ^= x0;
  x0 += x1; x1 = rotl32(x1,26); x1 ^= x0;
  x0 += x1; x1 = rotl32(x1, 6); x1 ^= x0;
  x0 += k1; x1 += ks2 + 1u;
  x0 += x1; x1 = rotl32(x1,17); x1 ^= x0;
  x0 += x1; x1 = rotl32(x1,29); x1 ^= x0;
  x0 += x1; x1 = rotl32(x1,16); x1 ^= x0;
  x0 += x1; x1 = rotl32(x1,24); x1 ^= x0;
  x0 += ks2; x1 += k0 + 2u;
  x0 += x1; x1 = rotl32(x1,13); x1 ^= x0;
  x0 += x1; x1 = rotl32(x1,15); x1 ^= x0;
  x0 += x1; x1 = rotl32(x1,26); x1 ^= x0;
  x0 += x1; x1 = rotl32(x1, 6); x1 ^= x0;
  x0 += k0; x1 += k1 + 3u;
  x0 += x1; x1 = rotl32(x1,17); x1 ^= x0;
  x0 += x1; x1 = rotl32(x1,29); x1 ^= x0;
  x0 += x1; x1 = rotl32(x1,16); x1 ^= x0;
  x0 += x1; x1 = rotl32(x1,24); x1 ^= x0;
  x0 += k1; x1 += ks2 + 4u;
  x0 += x1; x1 = rotl32(x1,13); x1 ^= x0;
  x0 += x1; x1 = rotl32(x1,15); x1 ^= x0;
  x0 += x1; x1 = rotl32(x1,26); x1 ^= x0;
  x0 += x1; x1 = rotl32(x1, 6); x1 ^= x0;
  x0 += ks2; x1 += k0 + 5u;
  o0 = x0; o1 = x1;
}

// partitionable-threefry randint(key(1), ..., 0, 100) == 0 for flat element idx
__device__ __forceinline__ bool jax_rand01(unsigned int idx,
                                           unsigned int k1a, unsigned int k1b,
                                           unsigned int k2a, unsigned int k2b){
  unsigned int h0, h1, l0, l1;
  tf2x32(k1a, k1b, 0u, idx, h0, h1);   // higher_bits[i] = b1^b2 of tf(k1,(0,i))
  tf2x32(k2a, k2b, 0u, idx, l0, l1);   // lower_bits[i]  = b1^b2 of tf(k2,(0,i))
  unsigned int h = h0 ^ h1;
  unsigned int l = l0 ^ l1;
  unsigned int off = ((h % 100u) * 96u + (l % 100u)) % 100u; // mult=(2^16%100)^2%100=96
  return off == 0u;
}

// ---------------- Kernel 1: dense softmax column-sums per query group ----------------
__global__ __launch_bounds__(256) void k1_colsum(const float* __restrict__ Q,
                                                 const float* __restrict__ K){
  const int bid = blockIdx.x, h = bid / QGg, g = bid % QGg, t = threadIdx.x;
  __shared__ float q_s[BMq][Dd+4];
  __shared__ float k_s[CK][Dd+4];
  __shared__ float s_s[BMq][CK+1];
  __shared__ float m_s[BMq];
  __shared__ float l_s[BMq];

  const float* qb = Q + ((size_t)h*Nn + (size_t)g*BMq)*Dd;
  #pragma unroll
  for (int it = 0; it < 8; ++it){
    int e = it*256 + t;                 // 2048 float4s
    int row = e >> 5, c4 = e & 31;
    float4 vq = ((const float4*)qb)[e];
    float4 sv; sv.x = vq.x*SCALE; sv.y = vq.y*SCALE; sv.z = vq.z*SCALE; sv.w = vq.w*SCALE;
    *(float4*)&q_s[row][c4*4] = sv;
  }
  if (t < BMq){ m_s[t] = -3.0e38f; l_s[t] = 0.0f; }
  __syncthreads();

  const int rt = t & 15, kt = t >> 4;

  // pass 1: row max / sumexp
  for (int j0 = 0; j0 < Nn; j0 += CK){
    const float* kb = K + ((size_t)h*Nn + j0)*Dd;
    #pragma unroll
    for (int it = 0; it < 4; ++it){
      int e = it*256 + t;               // 1024 float4s
      int row = e >> 5, c4 = e & 31;
      *(float4*)&k_s[row][c4*4] = ((const float4*)kb)[e];
    }
    __syncthreads();
    float acc[4][2] = {};
    const int kcol = kt*2;
    for (int d = 0; d < Dd; d += 4){
      float4 ka = *(const float4*)&k_s[kcol][d];
      float4 kb2 = *(const float4*)&k_s[kcol+1][d];
      #pragma unroll
      for (int rr = 0; rr < 4; ++rr){
        float4 qv = *(const float4*)&q_s[rr*16+rt][d];
        acc[rr][0] += qv.x*ka.x + qv.y*ka.y + qv.z*ka.z + qv.w*ka.w;
        acc[rr][1] += qv.x*kb2.x + qv.y*kb2.y + qv.z*kb2.z + qv.w*kb2.w;
      }
    }
    #pragma unroll
    for (int rr = 0; rr < 4; ++rr){
      s_s[rr*16+rt][kcol]   = acc[rr][0];
      s_s[rr*16+rt][kcol+1] = acc[rr][1];
    }
    __syncthreads();
    if (t < BMq){
      float m = m_s[t], l = l_s[t];
      for (int c2 = 0; c2 < CK; ++c2){
        float s = s_s[t][c2];
        float nm = fmaxf(m, s);
        l = l * expf(m - nm) + expf(s - nm);
        m = nm;
      }
      m_s[t] = m; l_s[t] = l;
    }
    __syncthreads();
  }
  if (t < BMq) l_s[t] = 1.0f / l_s[t];
  __syncthreads();

  // pass 2: recompute scores, column-sum normalized probs
  for (int j0 = 0; j0 < Nn; j0 += CK){
    const float* kb = K + ((size_t)h*Nn + j0)*Dd;
    #pragma unroll
    for (int it = 0; it < 4; ++it){
      int e = it*256 + t;
      int row = e >> 5, c4 = e & 31;
      *(float4*)&k_s[row][c4*4] = ((const float4*)kb)[e];
    }
    __syncthreads();
    float acc[4][2] = {};
    const int kcol = kt*2;
    for (int d = 0; d < Dd; d += 4){
      float4 ka = *(const float4*)&k_s[kcol][d];
      float4 kb2 = *(const float4*)&k_s[kcol+1][d];
      #pragma unroll
      for (int rr = 0; rr < 4; ++rr){
        float4 qv = *(const float4*)&q_s[rr*16+rt][d];
        acc[rr][0] += qv.x*ka.x + qv.y*ka.y + qv.z*ka.z + qv.w*ka.w;
        acc[rr][1] += qv.x*kb2.x + qv.y*kb2.y + qv.z*kb2.z + qv.w*kb2.w;
      }
    }
    #pragma unroll
    for (int rr = 0; rr < 4; ++rr){
      s_s[rr*16+rt][kcol]   = acc[rr][0];
      s_s[rr*16+rt][kcol+1] = acc[rr][1];
    }
    __syncthreads();
    if (t < CK){
      float sum = 0.f;
      for (int r = 0; r < BMq; ++r)
        sum += expf(s_s[r][t] - m_s[r]) * l_s[r];
      g_bs[(size_t)bid*Nn + j0 + t] = sum;
    }
    __syncthreads();
  }
}

// ---------------- Kernel 2: top-k + random + static window -> compacted key list ----------------
__global__ __launch_bounds__(256) void k2_mask(){
  const int bid = blockIdx.x, g = bid % QGg, t = threadIdx.x;
  __shared__ float bsv[Nn];
  __shared__ int red;
  __shared__ int csel;
  const float* src = g_bs + (size_t)bid*Nn;
  #pragma unroll
  for (int it = 0; it < 8; ++it) bsv[it*256 + t] = src[it*256 + t];
  if (t == 0){ red = 0; csel = 0; }
  __syncthreads();

  // fold-like split(key(1)): child i = tf((0,1),(0,i))
  unsigned int k1a, k1b, k2a, k2b;
  tf2x32(0u, 1u, 0u, 0u, k1a, k1b);
  tf2x32(0u, 1u, 0u, 1u, k2a, k2b);

  // 192nd-largest value via bitwise binary search (values positive -> uint order)
  unsigned int prefix = 0u;
  for (int bit = 31; bit >= 0; --bit){
    unsigned int cand = prefix | (1u << bit);
    int c = 0;
    #pragma unroll
    for (int it = 0; it < 8; ++it)
      c += (__float_as_uint(bsv[it*256 + t]) >= cand) ? 1 : 0;
    #pragma unroll
    for (int off = 32; off > 0; off >>= 1) c += __shfl_down(c, off);
    if ((t & 63) == 0) atomicAdd(&red, c);
    __syncthreads();
    int total = red;
    __syncthreads();
    if (t == 0) red = 0;
    __syncthreads();
    if (total >= KSEL) prefix = cand;
  }
  // count strictly-greater to size the tie budget
  {
    int cg = 0;
    #pragma unroll
    for (int it = 0; it < 8; ++it)
      cg += (__float_as_uint(bsv[it*256 + t]) > prefix) ? 1 : 0;
    #pragma unroll
    for (int off = 32; off > 0; off >>= 1) cg += __shfl_down(cg, off);
    if ((t & 63) == 0) atomicAdd(&red, cg);
  }
  __syncthreads();
  const int need = KSEL - red;   // ties taken lowest-index-first (jax top_k)

  const int lo = g*BMq + BMq/2 - 153;   // ws=int(0.15*2048)=307, ws//2=153
  const int hi = g*BMq + BMq/2 + 153;
  const int ssum = ((hi < Nn) ? hi : Nn) - ((lo > 0) ? lo : 0);
  const bool vqg = (ssum + KSEL) < Nn;  // always true at this config

  for (int it = 0; it < 8; ++it){
    int j = it*256 + t;
    unsigned int bu = __float_as_uint(bsv[j]);
    bool topk = bu > prefix;
    if (!topk && bu == prefix){
      int tr = 0;
      for (int jj = 0; jj < j; ++jj)
        tr += (__float_as_uint(bsv[jj]) == prefix) ? 1 : 0;
      topk = (tr < need);
    }
    bool rnd = jax_rand01((unsigned)(bid*Nn + j), k1a, k1b, k2a, k2b);
    bool st  = (j >= lo) && (j < hi);
    bool selb = st || ((rnd || topk) && vqg);
    if (selb){
      int slot = atomicAdd(&csel, 1);
      g_sel[(size_t)bid*Nn + slot] = (unsigned short)j;
    }
  }
  __syncthreads();
  if (t == 0) g_cnt[bid] = csel;
}

// ---------------- Kernel 3: masked attention over selected keys + out_cache ----------------
__global__ __launch_bounds__(256) void k3_attn(const float* __restrict__ Q,
                                               const float* __restrict__ K,
                                               const float* __restrict__ V,
                                               const float* __restrict__ OC,
                                               float* __restrict__ out){
  const int bid = blockIdx.x, h = bid / QGg, g = bid % QGg, t = threadIdx.x;
  __shared__ float q_s[BMq][Dd+4];
  __shared__ float kv_s[CK][Dd+4];
  __shared__ float s_s[BMq][CK+1];
  __shared__ float m_s[BMq];
  __shared__ float l_s[BMq];
  const int c = g_cnt[bid];
  const unsigned short* sel = g_sel + (size_t)bid*Nn;

  const float* qb = Q + ((size_t)h*Nn + (size_t)g*BMq)*Dd;
  #pragma unroll
  for (int it = 0; it < 8; ++it){
    int e = it*256 + t;
    int row = e >> 5, c4 = e & 31;
    float4 vq = ((const float4*)qb)[e];
    float4 sv; sv.x = vq.x*SCALE; sv.y = vq.y*SCALE; sv.z = vq.z*SCALE; sv.w = vq.w*SCALE;
    *(float4*)&q_s[row][c4*4] = sv;
  }
  if (t < BMq){ m_s[t] = -3.0e38f; l_s[t] = 0.0f; }
  __syncthreads();

  const int rt = t & 15, kt = t >> 4;

  // phase 1: masked-softmax stats over selected keys
  for (int c0 = 0; c0 < c; c0 += CK){
    const int cc = ((c - c0) < CK) ? (c - c0) : CK;
    #pragma unroll
    for (int it = 0; it < 4; ++it){
      int e = it*256 + t;
      int row = e >> 5, c4 = e & 31;
      int j = (row < cc) ? (int)sel[c0 + row] : 0;
      *(float4*)&kv_s[row][c4*4] = ((const float4*)(K + ((size_t)h*Nn + j)*Dd))[c4];
    }
    __syncthreads();
    float acc[4][2] = {};
    const int kcol = kt*2;
    for (int d = 0; d < Dd; d += 4){
      float4 ka = *(const float4*)&kv_s[kcol][d];
      float4 kb2 = *(const float4*)&kv_s[kcol+1][d];
      #pragma unroll
      for (int rr = 0; rr < 4; ++rr){
        float4 qv = *(const float4*)&q_s[rr*16+rt][d];
        acc[rr][0] += qv.x*ka.x + qv.y*ka.y + qv.z*ka.z + qv.w*ka.w;
        acc[rr][1] += qv.x*kb2.x + qv.y*kb2.y + qv.z*kb2.z + qv.w*kb2.w;
      }
    }
    #pragma unroll
    for (int rr = 0; rr < 4; ++rr){
      s_s[rr*16+rt][kcol]   = acc[rr][0];
      s_s[rr*16+rt][kcol+1] = acc[rr][1];
    }
    __syncthreads();
    if (t < BMq){
      float m = m_s[t], l = l_s[t];
      for (int c2 = 0; c2 < cc; ++c2){
        float s = s_s[t][c2];
        float nm = fmaxf(m, s);
        l = l * expf(m - nm) + expf(s - nm);
        m = nm;
      }
      m_s[t] = m; l_s[t] = l;
    }
    __syncthreads();
  }
  if (t < BMq) l_s[t] = 1.0f / l_s[t];
  __syncthreads();

  // phase 2: P·V accumulate
  float acc2[4][8] = {};
  const int dg = t >> 4, d0 = dg*8;
  for (int c0 = 0; c0 < c; c0 += CK){
    const int cc = ((c - c0) < CK) ? (c - c0) : CK;
    #pragma unroll
    for (int it = 0; it < 4; ++it){
      int e = it*256 + t;
      int row = e >> 5, c4 = e & 31;
      int j = (row < cc) ? (int)sel[c0 + row] : 0;
      *(float4*)&kv_s[row][c4*4] = ((const float4*)(K + ((size_t)h*Nn + j)*Dd))[c4];
    }
    __syncthreads();
    float acc[4][2] = {};
    const int kcol = kt*2;
    for (int d = 0; d < Dd; d += 4){
      float4 ka = *(const float4*)&kv_s[kcol][d];
      float4 kb2 = *(const float4*)&kv_s[kcol+1][d];
      #pragma unroll
      for (int rr = 0; rr < 4; ++rr){
        float4 qv = *(const float4*)&q_s[rr*16+rt][d];
        acc[rr][0] += qv.x*ka.x + qv.y*ka.y + qv.z*ka.z + qv.w*ka.w;
        acc[rr][1] += qv.x*kb2.x + qv.y*kb2.y + qv.z*kb2.z + qv.w*kb2.w;
      }
    }
    #pragma unroll
    for (int rr = 0; rr < 4; ++rr){
      s_s[rr*16+rt][kcol]   = acc[rr][0];
      s_s[rr*16+rt][kcol+1] = acc[rr][1];
    }
    __syncthreads();
    // scores -> probs in place; then gather V into kv_s
    for (int e = t; e < BMq*CK; e += 256){
      int row = e >> 5, c2 = e & 31;
      float p = 0.f;
      if (c2 < cc) p = expf(s_s[row][c2] - m_s[row]) * l_s[row];
      s_s[row][c2] = p;
    }
    #pragma unroll
    for (int it = 0; it < 4; ++it){
      int e = it*256 + t;
      int row = e >> 5, c4 = e & 31;
      int j = (row < cc) ? (int)sel[c0 + row] : 0;
      *(float4*)&kv_s[row][c4*4] = ((const float4*)(V + ((size_t)h*Nn + j)*Dd))[c4];
    }
    __syncthreads();
    for (int c2 = 0; c2 < cc; ++c2){
      float pv[4];
      #pragma unroll
      for (int rr = 0; rr < 4; ++rr) pv[rr] = s_s[rr*16+rt][c2];
      float4 va = *(const float4*)&kv_s[c2][d0];
      float4 vb = *(const float4*)&kv_s[c2][d0+4];
      #pragma unroll
      for (int rr = 0; rr < 4; ++rr){
        acc2[rr][0] += pv[rr]*va.x; acc2[rr][1] += pv[rr]*va.y;
        acc2[rr][2] += pv[rr]*va.z; acc2[rr][3] += pv[rr]*va.w;
        acc2[rr][4] += pv[rr]*vb.x; acc2[rr][5] += pv[rr]*vb.y;
        acc2[rr][6] += pv[rr]*vb.z; acc2[rr][7] += pv[rr]*vb.w;
      }
    }
    __syncthreads();
  }

  #pragma unroll
  for (int rr = 0; rr < 4; ++rr){
    const int r = rr*16 + rt;
    size_t o = ((size_t)h*Nn + (size_t)g*BMq + r)*Dd + d0;
    float4 ca = *(const float4*)(OC + o);
    float4 cb = *(const float4*)(OC + o + 4);
    float4 ra, rb;
    ra.x = acc2[rr][0] + ca.x; ra.y = acc2[rr][1] + ca.y;
    ra.z = acc2[rr][2] + ca.z; ra.w = acc2[rr][3] + ca.w;
    rb.x = acc2[rr][4] + cb.x; rb.y = acc2[rr][5] + cb.y;
    rb.z = acc2[rr][6] + cb.z; rb.w = acc2[rr][7] + cb.w;
    *(float4*)(out + o)     = ra;
    *(float4*)(out + o + 4) = rb;
  }
}

extern "C" void kernel_launch(void* const* d_in, const int* in_sizes, int n_in,
                              void* d_out, int out_size, void* d_ws, size_t ws_size,
                              hipStream_t stream) {
  (void)in_sizes; (void)n_in; (void)out_size; (void)d_ws; (void)ws_size;
  const float* Q  = (const float*)d_in[0];
  const float* K  = (const float*)d_in[1];
  const float* V  = (const float*)d_in[2];
  const float* OC = (const float*)d_in[3];
  float* out = (float*)d_out;
  hipLaunchKernelGGL(k1_colsum, dim3(Hh*QGg), dim3(256), 0, stream, Q, K);
  hipLaunchKernelGGL(k2_mask,   dim3(Hh*QGg), dim3(256), 0, stream);
  hipLaunchKernelGGL(k3_attn,   dim3(Hh*QGg), dim3(256), 0, stream, Q, K, V, OC, out);
}

// Round 5
// 955.612 us; speedup vs baseline: 1.6107x; 1.6107x over previous
//
#include <hip/hip_runtime.h>
#include <math.h>

// SparseDiffAttn: B=1,H=12,N=2048,D=128, BM=64, top-k=192, static window [c-153,c+153),
// random keys via modern-JAX randint under jax_threefry_partitionable=True:
//   k1 = tf((0,1),(0,0)), k2 = tf((0,1),(0,1))        [fold-like split]
//   bits(k,i) = b1^b2 with (b1,b2) = tf(k,(0,i))      [partitionable random_bits]
//   offset = ((hi%100)*96 + lo%100) % 100; rnd <=> offset==0
constexpr int Hh   = 12;
constexpr int Nn   = 2048;
constexpr int Dd   = 128;
constexpr int BMq  = 64;
constexpr int QGg  = 32;            // Nn/BMq
constexpr int KSEL = 192;           // 64 * round(0.1*2048/64)
constexpr int CK   = 32;            // key chunk (k3)
constexpr int DC   = 32;            // d-chunk (k1a)
constexpr int LSTR = 132;           // padded LDS row stride (floats)
constexpr float SCALE = 0.08838834764831845f;  // 1/sqrt(128)

// persistent scratch (fully rewritten every launch before any read)
__device__ float          g_E [(size_t)Hh*Nn*Nn];   // 201 MB: exp(score), [h*2048+row][j]
__device__ float          g_lp[(size_t)Hh*Nn*16];   // per-jb partial row sums
__device__ unsigned short g_sel[Hh*QGg*Nn];
__device__ int            g_cnt[Hh*QGg];

__device__ __forceinline__ unsigned int rotl32(unsigned int x, int n){
  return (x << n) | (x >> (32 - n));
}

// threefry2x32, 20 rounds, arbitrary key
__device__ __forceinline__ void tf2x32(unsigned int k0, unsigned int k1,
                                       unsigned int x0, unsigned int x1,
                                       unsigned int &o0, unsigned int &o1){
  const unsigned int ks2 = 0x1BD11BDAu ^ k0 ^ k1;
  x0 += k0; x1 += k1;
  x0 += x1; x1 = rotl32(x1,13); x1 ^= x0;
  x0 += x1; x1 = rotl32(x1,15); x1 ^= x0;
  x0 += x1; x1 = rotl32(x1,26); x1 ^= x0;
  x0 += x1; x1 = rotl32(x1, 6); x1 ^= x0;
  x0 += k1; x1 += ks2 + 1u;
  x0 += x1; x1 = rotl32(x1,17); x1 ^= x0;
  x0 += x1; x1 = rotl32(x1,29); x1 ^= x0;
  x0 += x1; x1 = rotl32(x1,16); x1 ^= x0;
  x0 += x1; x1 = rotl32(x1,24); x1 ^= x0;
  x0 += ks2; x1 += k0 + 2u;
  x0 += x1; x1 = rotl32(x1,13); x1 ^= x0;
  x0 += x1; x1 = rotl32(x1,15); x1 ^= x0;
  x0 += x1; x1 = rotl32(x1,26); x1 ^= x0;
  x0 += x1; x1 = rotl32(x1, 6); x1 ^= x0;
  x0 += k0; x1 += k1 + 3u;
  x0 += x1; x1 = rotl32(x1,17); x1 ^= x0;
  x0 += x1; x1 = rotl32(x1,29); x1 ^= x0;
  x0 += x1; x1 = rotl32(x1,16); x1 ^= x0;
  x0 += x1; x1 = rotl32(x1,24); x1 ^= x0;
  x0 += k1; x1 += ks2 + 4u;
  x0 += x1; x1 = rotl32(x1,13); x1 ^= x0;
  x0 += x1; x1 = rotl32(x1,15); x1 ^= x0;
  x0 += x1; x1 = rotl32(x1,26); x1 ^= x0;
  x0 += x1; x1 = rotl32(x1, 6); x1 ^= x0;
  x0 += ks2; x1 += k0 + 5u;
  o0 = x0; o1 = x1;
}

// partitionable-threefry randint(key(1), ..., 0, 100) == 0 for flat element idx
__device__ __forceinline__ bool jax_rand01(unsigned int idx,
                                           unsigned int k1a, unsigned int k1b,
                                           unsigned int k2a, unsigned int k2b){
  unsigned int h0, h1, l0, l1;
  tf2x32(k1a, k1b, 0u, idx, h0, h1);
  tf2x32(k2a, k2b, 0u, idx, l0, l1);
  unsigned int h = h0 ^ h1;
  unsigned int l = l0 ^ l1;
  unsigned int off = ((h % 100u) * 96u + (l % 100u)) % 100u;
  return off == 0u;
}

// ---------------- Kernel 1a: one-pass E=exp(QK^T*scale) + partial row sums ----------------
// 128 rows x 128 cols per block, 8x8 micro-tile, d in 32-chunks, reg-prefetched staging.
__global__ __launch_bounds__(256) void k1a_scores(const float* __restrict__ Q,
                                                  const float* __restrict__ K){
  const int bid = blockIdx.x;
  const int jb = bid & 15, gp = (bid >> 4) & 15, h = bid >> 8;
  const int t = threadIdx.x, tx = t & 15, ty = t >> 4;
  __shared__ float Qt[DC][LSTR];   // transposed, pre-scaled
  __shared__ float Kt[DC][LSTR];   // transposed
  __shared__ float lsum[128][17];

  const int R0 = gp*128, J0 = jb*128;
  const float* Qb = Q + ((size_t)h*Nn + R0)*Dd;
  const float* Kb = K + ((size_t)h*Nn + J0)*Dd;

  float acc[8][8] = {};
  float4 qreg[4], kreg[4];
  #pragma unroll
  for (int it = 0; it < 4; ++it){
    int e = it*256 + t, r = e >> 3, d4 = e & 7;   // r 0..127, d = d4*4
    qreg[it] = ((const float4*)(Qb + (size_t)r*Dd))[d4];
    kreg[it] = ((const float4*)(Kb + (size_t)r*Dd))[d4];
  }
  for (int c = 0; c < Dd/DC; ++c){
    #pragma unroll
    for (int it = 0; it < 4; ++it){
      int e = it*256 + t, r = e >> 3, d4 = e & 7;
      float4 qv = qreg[it], kv = kreg[it];
      Qt[d4*4+0][r] = qv.x*SCALE; Qt[d4*4+1][r] = qv.y*SCALE;
      Qt[d4*4+2][r] = qv.z*SCALE; Qt[d4*4+3][r] = qv.w*SCALE;
      Kt[d4*4+0][r] = kv.x; Kt[d4*4+1][r] = kv.y;
      Kt[d4*4+2][r] = kv.z; Kt[d4*4+3][r] = kv.w;
    }
    __syncthreads();
    if (c < Dd/DC - 1){
      const int d0 = (c+1)*DC;
      #pragma unroll
      for (int it = 0; it < 4; ++it){
        int e = it*256 + t, r = e >> 3, d4 = e & 7;
        qreg[it] = ((const float4*)(Qb + (size_t)r*Dd + d0))[d4];
        kreg[it] = ((const float4*)(Kb + (size_t)r*Dd + d0))[d4];
      }
    }
    #pragma unroll 8
    for (int dd = 0; dd < DC; ++dd){
      float a[8], b[8];
      *(float4*)&a[0] = *(const float4*)&Qt[dd][ty*8];
      *(float4*)&a[4] = *(const float4*)&Qt[dd][ty*8+4];
      *(float4*)&b[0] = *(const float4*)&Kt[dd][tx*8];
      *(float4*)&b[4] = *(const float4*)&Kt[dd][tx*8+4];
      #pragma unroll
      for (int i = 0; i < 8; ++i)
        #pragma unroll
        for (int j = 0; j < 8; ++j)
          acc[i][j] += a[i]*b[j];
    }
    __syncthreads();
  }

  // E = expf(acc) -> g_E; partial row sums -> lsum -> g_lp
  #pragma unroll
  for (int i = 0; i < 8; ++i){
    const int r = ty*8 + i;
    float ev[8]; float s = 0.f;
    #pragma unroll
    for (int j = 0; j < 8; ++j){ ev[j] = expf(acc[i][j]); s += ev[j]; }
    lsum[r][tx] = s;
    float4 e0, e1;
    e0.x=ev[0]; e0.y=ev[1]; e0.z=ev[2]; e0.w=ev[3];
    e1.x=ev[4]; e1.y=ev[5]; e1.z=ev[6]; e1.w=ev[7];
    float* Ep = &g_E[((size_t)h*Nn + R0 + r)*Nn + J0 + tx*8];
    *(float4*)Ep = e0;
    *(float4*)(Ep+4) = e1;
  }
  __syncthreads();
  if (t < 128){
    float s = 0.f;
    #pragma unroll
    for (int x = 0; x < 16; ++x) s += lsum[t][x];
    g_lp[((size_t)h*Nn + R0 + t)*16 + jb] = s;
  }
}

// ---------------- Kernel 2: bs colsum from E + top-k + random + static -> key list ----------------
__global__ __launch_bounds__(256) void k2_mask(){
  const int bid = blockIdx.x, h = bid / QGg, g = bid % QGg, t = threadIdx.x;
  __shared__ float bsv[Nn];
  __shared__ float il[BMq];
  __shared__ int red;
  __shared__ int csel;
  if (t < BMq){
    const float* lp = &g_lp[((size_t)h*Nn + g*BMq + t)*16];
    float s = 0.f;
    #pragma unroll
    for (int x = 0; x < 16; ++x) s += lp[x];
    il[t] = 1.0f / s;
  }
  if (t == 0){ red = 0; csel = 0; }
  __syncthreads();

  // bs_j = sum_r E[row r][j] * il[r]   (coalesced over j)
  #pragma unroll
  for (int i = 0; i < 8; ++i){
    int j = i*256 + t;
    const float* Ep = &g_E[((size_t)h*Nn + g*BMq)*Nn + j];
    float s = 0.f;
    for (int r = 0; r < BMq; ++r) s += Ep[(size_t)r*Nn] * il[r];
    bsv[j] = s;
  }
  __syncthreads();

  // fold-like split(key(1)): child i = tf((0,1),(0,i))
  unsigned int k1a, k1b, k2a, k2b;
  tf2x32(0u, 1u, 0u, 0u, k1a, k1b);
  tf2x32(0u, 1u, 0u, 1u, k2a, k2b);

  // 192nd-largest value via bitwise binary search (values positive -> uint order)
  unsigned int prefix = 0u;
  for (int bit = 31; bit >= 0; --bit){
    unsigned int cand = prefix | (1u << bit);
    int c = 0;
    #pragma unroll
    for (int it = 0; it < 8; ++it)
      c += (__float_as_uint(bsv[it*256 + t]) >= cand) ? 1 : 0;
    #pragma unroll
    for (int off = 32; off > 0; off >>= 1) c += __shfl_down(c, off);
    if ((t & 63) == 0) atomicAdd(&red, c);
    __syncthreads();
    int total = red;
    __syncthreads();
    if (t == 0) red = 0;
    __syncthreads();
    if (total >= KSEL) prefix = cand;
  }
  {
    int cg = 0;
    #pragma unroll
    for (int it = 0; it < 8; ++it)
      cg += (__float_as_uint(bsv[it*256 + t]) > prefix) ? 1 : 0;
    #pragma unroll
    for (int off = 32; off > 0; off >>= 1) cg += __shfl_down(cg, off);
    if ((t & 63) == 0) atomicAdd(&red, cg);
  }
  __syncthreads();
  const int need = KSEL - red;   // ties taken lowest-index-first (jax top_k)

  const int lo = g*BMq + BMq/2 - 153;   // ws=int(0.15*2048)=307, ws//2=153
  const int hi = g*BMq + BMq/2 + 153;
  const int ssum = ((hi < Nn) ? hi : Nn) - ((lo > 0) ? lo : 0);
  const bool vqg = (ssum + KSEL) < Nn;  // always true at this config

  for (int it = 0; it < 8; ++it){
    int j = it*256 + t;
    unsigned int bu = __float_as_uint(bsv[j]);
    bool topk = bu > prefix;
    if (!topk && bu == prefix){
      int tr = 0;
      for (int jj = 0; jj < j; ++jj)
        tr += (__float_as_uint(bsv[jj]) == prefix) ? 1 : 0;
      topk = (tr < need);
    }
    bool rnd = jax_rand01((unsigned)(bid*Nn + j), k1a, k1b, k2a, k2b);
    bool st  = (j >= lo) && (j < hi);
    bool selb = st || ((rnd || topk) && vqg);
    if (selb){
      int slot = atomicAdd(&csel, 1);
      g_sel[(size_t)bid*Nn + slot] = (unsigned short)j;
    }
  }
  __syncthreads();
  if (t == 0) g_cnt[bid] = csel;
}

// ---------------- Kernel 3: masked attention over selected keys + out_cache ----------------
__global__ __launch_bounds__(256) void k3_attn(const float* __restrict__ Q,
                                               const float* __restrict__ K,
                                               const float* __restrict__ V,
                                               const float* __restrict__ OC,
                                               float* __restrict__ out){
  const int bid = blockIdx.x, h = bid / QGg, g = bid % QGg, t = threadIdx.x;
  __shared__ float q_s[BMq][Dd+4];
  __shared__ float kv_s[CK][Dd+4];
  __shared__ float s_s[BMq][CK+1];
  __shared__ float m_s[BMq];
  __shared__ float l_s[BMq];
  const int c = g_cnt[bid];
  const unsigned short* sel = g_sel + (size_t)bid*Nn;

  const float* qb = Q + ((size_t)h*Nn + (size_t)g*BMq)*Dd;
  #pragma unroll
  for (int it = 0; it < 8; ++it){
    int e = it*256 + t;
    int row = e >> 5, c4 = e & 31;
    float4 vq = ((const float4*)qb)[e];
    float4 sv; sv.x = vq.x*SCALE; sv.y = vq.y*SCALE; sv.z = vq.z*SCALE; sv.w = vq.w*SCALE;
    *(float4*)&q_s[row][c4*4] = sv;
  }
  if (t < BMq){ m_s[t] = -3.0e38f; l_s[t] = 0.0f; }
  __syncthreads();

  const int rt = t & 15, kt = t >> 4;

  // phase 1: masked-softmax stats over selected keys
  for (int c0 = 0; c0 < c; c0 += CK){
    const int cc = ((c - c0) < CK) ? (c - c0) : CK;
    #pragma unroll
    for (int it = 0; it < 4; ++it){
      int e = it*256 + t;
      int row = e >> 5, c4 = e & 31;
      int j = (row < cc) ? (int)sel[c0 + row] : 0;
      *(float4*)&kv_s[row][c4*4] = ((const float4*)(K + ((size_t)h*Nn + j)*Dd))[c4];
    }
    __syncthreads();
    float acc[4][2] = {};
    const int kcol = kt*2;
    for (int d = 0; d < Dd; d += 4){
      float4 ka = *(const float4*)&kv_s[kcol][d];
      float4 kb2 = *(const float4*)&kv_s[kcol+1][d];
      #pragma unroll
      for (int rr = 0; rr < 4; ++rr){
        float4 qv = *(const float4*)&q_s[rr*16+rt][d];
        acc[rr][0] += qv.x*ka.x + qv.y*ka.y + qv.z*ka.z + qv.w*ka.w;
        acc[rr][1] += qv.x*kb2.x + qv.y*kb2.y + qv.z*kb2.z + qv.w*kb2.w;
      }
    }
    #pragma unroll
    for (int rr = 0; rr < 4; ++rr){
      s_s[rr*16+rt][kcol]   = acc[rr][0];
      s_s[rr*16+rt][kcol+1] = acc[rr][1];
    }
    __syncthreads();
    if (t < BMq){
      float m = m_s[t], l = l_s[t];
      for (int c2 = 0; c2 < cc; ++c2){
        float s = s_s[t][c2];
        float nm = fmaxf(m, s);
        l = l * expf(m - nm) + expf(s - nm);
        m = nm;
      }
      m_s[t] = m; l_s[t] = l;
    }
    __syncthreads();
  }
  if (t < BMq) l_s[t] = 1.0f / l_s[t];
  __syncthreads();

  // phase 2: P·V accumulate
  float acc2[4][8] = {};
  const int dg = t >> 4, d0 = dg*8;
  for (int c0 = 0; c0 < c; c0 += CK){
    const int cc = ((c - c0) < CK) ? (c - c0) : CK;
    #pragma unroll
    for (int it = 0; it < 4; ++it){
      int e = it*256 + t;
      int row = e >> 5, c4 = e & 31;
      int j = (row < cc) ? (int)sel[c0 + row] : 0;
      *(float4*)&kv_s[row][c4*4] = ((const float4*)(K + ((size_t)h*Nn + j)*Dd))[c4];
    }
    __syncthreads();
    float acc[4][2] = {};
    const int kcol = kt*2;
    for (int d = 0; d < Dd; d += 4){
      float4 ka = *(const float4*)&kv_s[kcol][d];
      float4 kb2 = *(const float4*)&kv_s[kcol+1][d];
      #pragma unroll
      for (int rr = 0; rr < 4; ++rr){
        float4 qv = *(const float4*)&q_s[rr*16+rt][d];
        acc[rr][0] += qv.x*ka.x + qv.y*ka.y + qv.z*ka.z + qv.w*ka.w;
        acc[rr][1] += qv.x*kb2.x + qv.y*kb2.y + qv.z*kb2.z + qv.w*kb2.w;
      }
    }
    #pragma unroll
    for (int rr = 0; rr < 4; ++rr){
      s_s[rr*16+rt][kcol]   = acc[rr][0];
      s_s[rr*16+rt][kcol+1] = acc[rr][1];
    }
    __syncthreads();
    // scores -> probs in place; then gather V into kv_s
    for (int e = t; e < BMq*CK; e += 256){
      int row = e >> 5, c2 = e & 31;
      float p = 0.f;
      if (c2 < cc) p = expf(s_s[row][c2] - m_s[row]) * l_s[row];
      s_s[row][c2] = p;
    }
    #pragma unroll
    for (int it = 0; it < 4; ++it){
      int e = it*256 + t;
      int row = e >> 5, c4 = e & 31;
      int j = (row < cc) ? (int)sel[c0 + row] : 0;
      *(float4*)&kv_s[row][c4*4] = ((const float4*)(V + ((size_t)h*Nn + j)*Dd))[c4];
    }
    __syncthreads();
    for (int c2 = 0; c2 < cc; ++c2){
      float pv[4];
      #pragma unroll
      for (int rr = 0; rr < 4; ++rr) pv[rr] = s_s[rr*16+rt][c2];
      float4 va = *(const float4*)&kv_s[c2][d0];
      float4 vb = *(const float4*)&kv_s[c2][d0+4];
      #pragma unroll
      for (int rr = 0; rr < 4; ++rr){
        acc2[rr][0] += pv[rr]*va.x; acc2[rr][1] += pv[rr]*va.y;
        acc2[rr][2] += pv[rr]*va.z; acc2[rr][3] += pv[rr]*va.w;
        acc2[rr][4] += pv[rr]*vb.x; acc2[rr][5] += pv[rr]*vb.y;
        acc2[rr][6] += pv[rr]*vb.z; acc2[rr][7] += pv[rr]*vb.w;
      }
    }
    __syncthreads();
  }

  #pragma unroll
  for (int rr = 0; rr < 4; ++rr){
    const int r = rr*16 + rt;
    size_t o = ((size_t)h*Nn + (size_t)g*BMq + r)*Dd + d0;
    float4 ca = *(const float4*)(OC + o);
    float4 cb = *(const float4*)(OC + o + 4);
    float4 ra, rb;
    ra.x = acc2[rr][0] + ca.x; ra.y = acc2[rr][1] + ca.y;
    ra.z = acc2[rr][2] + ca.z; ra.w = acc2[rr][3] + ca.w;
    rb.x = acc2[rr][4] + cb.x; rb.y = acc2[rr][5] + cb.y;
    rb.z = acc2[rr][6] + cb.z; rb.w = acc2[rr][7] + cb.w;
    *(float4*)(out + o)     = ra;
    *(float4*)(out + o + 4) = rb;
  }
}

extern "C" void kernel_launch(void* const* d_in, const int* in_sizes, int n_in,
                              void* d_out, int out_size, void* d_ws, size_t ws_size,
                              hipStream_t stream) {
  (void)in_sizes; (void)n_in; (void)out_size; (void)d_ws; (void)ws_size;
  const float* Q  = (const float*)d_in[0];
  const float* K  = (const float*)d_in[1];
  const float* V  = (const float*)d_in[2];
  const float* OC = (const float*)d_in[3];
  float* out = (float*)d_out;
  hipLaunchKernelGGL(k1a_scores, dim3(Hh*16*16), dim3(256), 0, stream, Q, K);
  hipLaunchKernelGGL(k2_mask,    dim3(Hh*QGg),   dim3(256), 0, stream);
  hipLaunchKernelGGL(k3_attn,    dim3(Hh*QGg),   dim3(256), 0, stream, Q, K, V, OC, out);
}

// Round 6
// 770.487 us; speedup vs baseline: 1.9976x; 1.2403x over previous
//
#include <hip/hip_runtime.h>
#include <math.h>

// SparseDiffAttn: B=1,H=12,N=2048,D=128, BM=64, top-k=192, static window [c-153,c+153),
// random keys via modern-JAX randint under jax_threefry_partitionable=True:
//   k1 = tf((0,1),(0,0)), k2 = tf((0,1),(0,1))        [fold-like split]
//   bits(k,i) = b1^b2 with (b1,b2) = tf(k,(0,i))      [partitionable random_bits]
//   offset = ((hi%100)*96 + lo%100) % 100; rnd <=> offset==0
constexpr int Hh   = 12;
constexpr int Nn   = 2048;
constexpr int Dd   = 128;
constexpr int BMq  = 64;
constexpr int QGg  = 32;            // Nn/BMq
constexpr int KSEL = 192;           // 64 * round(0.1*2048/64)
constexpr int CK   = 32;            // key chunk (k3)
constexpr int DC   = 32;            // d-chunk (k1a)
constexpr int LSTR = 132;           // padded LDS row stride (floats)
constexpr float SCALE = 0.08838834764831845f;  // 1/sqrt(128)

// persistent scratch (fully rewritten every launch before any read)
__device__ float          g_E [(size_t)Hh*Nn*Nn];   // 201 MB: exp(score), [h*2048+row][j]
__device__ float          g_lp[(size_t)Hh*Nn*16];   // per-jb partial row sums
__device__ unsigned short g_sel[Hh*QGg*Nn];
__device__ int            g_cnt[Hh*QGg];

__device__ __forceinline__ unsigned int rotl32(unsigned int x, int n){
  return (x << n) | (x >> (32 - n));
}

// threefry2x32, 20 rounds, arbitrary key
__device__ __forceinline__ void tf2x32(unsigned int k0, unsigned int k1,
                                       unsigned int x0, unsigned int x1,
                                       unsigned int &o0, unsigned int &o1){
  const unsigned int ks2 = 0x1BD11BDAu ^ k0 ^ k1;
  x0 += k0; x1 += k1;
  x0 += x1; x1 = rotl32(x1,13); x1 ^= x0;
  x0 += x1; x1 = rotl32(x1,15); x1 ^= x0;
  x0 += x1; x1 = rotl32(x1,26); x1 ^= x0;
  x0 += x1; x1 = rotl32(x1, 6); x1 ^= x0;
  x0 += k1; x1 += ks2 + 1u;
  x0 += x1; x1 = rotl32(x1,17); x1 ^= x0;
  x0 += x1; x1 = rotl32(x1,29); x1 ^= x0;
  x0 += x1; x1 = rotl32(x1,16); x1 ^= x0;
  x0 += x1; x1 = rotl32(x1,24); x1 ^= x0;
  x0 += ks2; x1 += k0 + 2u;
  x0 += x1; x1 = rotl32(x1,13); x1 ^= x0;
  x0 += x1; x1 = rotl32(x1,15); x1 ^= x0;
  x0 += x1; x1 = rotl32(x1,26); x1 ^= x0;
  x0 += x1; x1 = rotl32(x1, 6); x1 ^= x0;
  x0 += k0; x1 += k1 + 3u;
  x0 += x1; x1 = rotl32(x1,17); x1 ^= x0;
  x0 += x1; x1 = rotl32(x1,29); x1 ^= x0;
  x0 += x1; x1 = rotl32(x1,16); x1 ^= x0;
  x0 += x1; x1 = rotl32(x1,24); x1 ^= x0;
  x0 += k1; x1 += ks2 + 4u;
  x0 += x1; x1 = rotl32(x1,13); x1 ^= x0;
  x0 += x1; x1 = rotl32(x1,15); x1 ^= x0;
  x0 += x1; x1 = rotl32(x1,26); x1 ^= x0;
  x0 += x1; x1 = rotl32(x1, 6); x1 ^= x0;
  x0 += ks2; x1 += k0 + 5u;
  o0 = x0; o1 = x1;
}

// partitionable-threefry randint(key(1), ..., 0, 100) == 0 for flat element idx
__device__ __forceinline__ bool jax_rand01(unsigned int idx,
                                           unsigned int k1a, unsigned int k1b,
                                           unsigned int k2a, unsigned int k2b){
  unsigned int h0, h1, l0, l1;
  tf2x32(k1a, k1b, 0u, idx, h0, h1);
  tf2x32(k2a, k2b, 0u, idx, l0, l1);
  unsigned int h = h0 ^ h1;
  unsigned int l = l0 ^ l1;
  unsigned int off = ((h % 100u) * 96u + (l % 100u)) % 100u;
  return off == 0u;
}

// ---------------- Kernel 1a: one-pass E=exp(QK^T*scale) + partial row sums ----------------
__global__ __launch_bounds__(256) void k1a_scores(const float* __restrict__ Q,
                                                  const float* __restrict__ K){
  const int bid = blockIdx.x;
  const int jb = bid & 15, gp = (bid >> 4) & 15, h = bid >> 8;
  const int t = threadIdx.x, tx = t & 15, ty = t >> 4;
  __shared__ float Qt[DC][LSTR];   // transposed, pre-scaled
  __shared__ float Kt[DC][LSTR];   // transposed
  __shared__ float lsum[128][17];

  const int R0 = gp*128, J0 = jb*128;
  const float* Qb = Q + ((size_t)h*Nn + R0)*Dd;
  const float* Kb = K + ((size_t)h*Nn + J0)*Dd;

  float acc[8][8] = {};
  float4 qreg[4], kreg[4];
  #pragma unroll
  for (int it = 0; it < 4; ++it){
    int e = it*256 + t, r = e >> 3, d4 = e & 7;
    qreg[it] = ((const float4*)(Qb + (size_t)r*Dd))[d4];
    kreg[it] = ((const float4*)(Kb + (size_t)r*Dd))[d4];
  }
  for (int c = 0; c < Dd/DC; ++c){
    #pragma unroll
    for (int it = 0; it < 4; ++it){
      int e = it*256 + t, r = e >> 3, d4 = e & 7;
      float4 qv = qreg[it], kv = kreg[it];
      Qt[d4*4+0][r] = qv.x*SCALE; Qt[d4*4+1][r] = qv.y*SCALE;
      Qt[d4*4+2][r] = qv.z*SCALE; Qt[d4*4+3][r] = qv.w*SCALE;
      Kt[d4*4+0][r] = kv.x; Kt[d4*4+1][r] = kv.y;
      Kt[d4*4+2][r] = kv.z; Kt[d4*4+3][r] = kv.w;
    }
    __syncthreads();
    if (c < Dd/DC - 1){
      const int d0 = (c+1)*DC;
      #pragma unroll
      for (int it = 0; it < 4; ++it){
        int e = it*256 + t, r = e >> 3, d4 = e & 7;
        qreg[it] = ((const float4*)(Qb + (size_t)r*Dd + d0))[d4];
        kreg[it] = ((const float4*)(Kb + (size_t)r*Dd + d0))[d4];
      }
    }
    #pragma unroll 8
    for (int dd = 0; dd < DC; ++dd){
      float a[8], b[8];
      *(float4*)&a[0] = *(const float4*)&Qt[dd][ty*8];
      *(float4*)&a[4] = *(const float4*)&Qt[dd][ty*8+4];
      *(float4*)&b[0] = *(const float4*)&Kt[dd][tx*8];
      *(float4*)&b[4] = *(const float4*)&Kt[dd][tx*8+4];
      #pragma unroll
      for (int i = 0; i < 8; ++i)
        #pragma unroll
        for (int j = 0; j < 8; ++j)
          acc[i][j] += a[i]*b[j];
    }
    __syncthreads();
  }

  #pragma unroll
  for (int i = 0; i < 8; ++i){
    const int r = ty*8 + i;
    float ev[8]; float s = 0.f;
    #pragma unroll
    for (int j = 0; j < 8; ++j){ ev[j] = expf(acc[i][j]); s += ev[j]; }
    lsum[r][tx] = s;
    float4 e0, e1;
    e0.x=ev[0]; e0.y=ev[1]; e0.z=ev[2]; e0.w=ev[3];
    e1.x=ev[4]; e1.y=ev[5]; e1.z=ev[6]; e1.w=ev[7];
    float* Ep = &g_E[((size_t)h*Nn + R0 + r)*Nn + J0 + tx*8];
    *(float4*)Ep = e0;
    *(float4*)(Ep+4) = e1;
  }
  __syncthreads();
  if (t < 128){
    float s = 0.f;
    #pragma unroll
    for (int x = 0; x < 16; ++x) s += lsum[t][x];
    g_lp[((size_t)h*Nn + R0 + t)*16 + jb] = s;
  }
}

// ---------------- Kernel 2: bs colsum from E + top-k + random + static -> key list ----------------
__global__ __launch_bounds__(256) void k2_mask(){
  const int bid = blockIdx.x, h = bid / QGg, g = bid % QGg, t = threadIdx.x;
  __shared__ float bsv[Nn];
  __shared__ float il[BMq];
  __shared__ int red;
  __shared__ int csel;
  if (t < BMq){
    const float* lp = &g_lp[((size_t)h*Nn + g*BMq + t)*16];
    float s = 0.f;
    #pragma unroll
    for (int x = 0; x < 16; ++x) s += lp[x];
    il[t] = 1.0f / s;
  }
  if (t == 0){ red = 0; csel = 0; }
  __syncthreads();

  #pragma unroll
  for (int i = 0; i < 8; ++i){
    int j = i*256 + t;
    const float* Ep = &g_E[((size_t)h*Nn + g*BMq)*Nn + j];
    float s = 0.f;
    for (int r = 0; r < BMq; ++r) s += Ep[(size_t)r*Nn] * il[r];
    bsv[j] = s;
  }
  __syncthreads();

  unsigned int k1a, k1b, k2a, k2b;
  tf2x32(0u, 1u, 0u, 0u, k1a, k1b);
  tf2x32(0u, 1u, 0u, 1u, k2a, k2b);

  unsigned int prefix = 0u;
  for (int bit = 31; bit >= 0; --bit){
    unsigned int cand = prefix | (1u << bit);
    int c = 0;
    #pragma unroll
    for (int it = 0; it < 8; ++it)
      c += (__float_as_uint(bsv[it*256 + t]) >= cand) ? 1 : 0;
    #pragma unroll
    for (int off = 32; off > 0; off >>= 1) c += __shfl_down(c, off);
    if ((t & 63) == 0) atomicAdd(&red, c);
    __syncthreads();
    int total = red;
    __syncthreads();
    if (t == 0) red = 0;
    __syncthreads();
    if (total >= KSEL) prefix = cand;
  }
  {
    int cg = 0;
    #pragma unroll
    for (int it = 0; it < 8; ++it)
      cg += (__float_as_uint(bsv[it*256 + t]) > prefix) ? 1 : 0;
    #pragma unroll
    for (int off = 32; off > 0; off >>= 1) cg += __shfl_down(cg, off);
    if ((t & 63) == 0) atomicAdd(&red, cg);
  }
  __syncthreads();
  const int need = KSEL - red;   // ties taken lowest-index-first (jax top_k)

  const int lo = g*BMq + BMq/2 - 153;   // ws=int(0.15*2048)=307, ws//2=153
  const int hi = g*BMq + BMq/2 + 153;
  const int ssum = ((hi < Nn) ? hi : Nn) - ((lo > 0) ? lo : 0);
  const bool vqg = (ssum + KSEL) < Nn;  // always true at this config

  for (int it = 0; it < 8; ++it){
    int j = it*256 + t;
    unsigned int bu = __float_as_uint(bsv[j]);
    bool topk = bu > prefix;
    if (!topk && bu == prefix){
      int tr = 0;
      for (int jj = 0; jj < j; ++jj)
        tr += (__float_as_uint(bsv[jj]) == prefix) ? 1 : 0;
      topk = (tr < need);
    }
    bool rnd = jax_rand01((unsigned)(bid*Nn + j), k1a, k1b, k2a, k2b);
    bool st  = (j >= lo) && (j < hi);
    bool selb = st || ((rnd || topk) && vqg);
    if (selb){
      int slot = atomicAdd(&csel, 1);
      g_sel[(size_t)bid*Nn + slot] = (unsigned short)j;
    }
  }
  __syncthreads();
  if (t == 0) g_cnt[bid] = csel;
}

// ---------------- Kernel 3: ONE-PASS masked attention (no-max exp trick) ----------------
// Block = 32 query rows (half of a group) x all selected keys. Grid = H*QG*2 = 768.
// LDS 38.1 KB -> 4 blocks/CU (16 waves/CU).
__global__ __launch_bounds__(256) void k3_attn(const float* __restrict__ Q,
                                               const float* __restrict__ K,
                                               const float* __restrict__ V,
                                               const float* __restrict__ OC,
                                               float* __restrict__ out){
  const int bid = blockIdx.x;
  const int half = bid & 1;
  const int gg   = bid >> 1;           // h*QGg + g
  const int h = gg / QGg, g = gg % QGg;
  const int t = threadIdx.x;
  __shared__ float q_s[32][Dd+4];
  __shared__ float kv_s[CK][Dd+4];
  __shared__ float s_s[32][CK+1];
  __shared__ float l_s[32];
  const int c = g_cnt[gg];
  const unsigned short* sel = g_sel + (size_t)gg*Nn;

  const float* qb = Q + ((size_t)h*Nn + (size_t)g*BMq + half*32)*Dd;
  #pragma unroll
  for (int it = 0; it < 4; ++it){
    int e = it*256 + t;                 // 1024 float4s = 32 rows x 32 f4
    int row = e >> 5, c4 = e & 31;
    float4 vq = ((const float4*)qb)[e];
    float4 sv; sv.x = vq.x*SCALE; sv.y = vq.y*SCALE; sv.z = vq.z*SCALE; sv.w = vq.w*SCALE;
    *(float4*)&q_s[row][c4*4] = sv;
  }
  if (t < 32) l_s[t] = 0.0f;
  __syncthreads();

  const int rt = t & 15, kt = t >> 4, kcol = kt*2;
  const int d0 = (t >> 4)*8;           // PV column group
  float acc2[2][8] = {};

  for (int c0 = 0; c0 < c; c0 += CK){
    const int cc = ((c - c0) < CK) ? (c - c0) : CK;
    // gather K chunk
    #pragma unroll
    for (int it = 0; it < 4; ++it){
      int e = it*256 + t, row = e >> 5, c4 = e & 31;
      int j = (row < cc) ? (int)sel[c0 + row] : 0;
      *(float4*)&kv_s[row][c4*4] = ((const float4*)(K + ((size_t)h*Nn + j)*Dd))[c4];
    }
    __syncthreads();
    // scores: rows {rt, rt+16} x cols {kcol, kcol+1}
    float a00=0.f, a01=0.f, a10=0.f, a11=0.f;
    #pragma unroll 8
    for (int d = 0; d < Dd; d += 4){
      float4 k0 = *(const float4*)&kv_s[kcol][d];
      float4 k1 = *(const float4*)&kv_s[kcol+1][d];
      float4 q0 = *(const float4*)&q_s[rt][d];
      float4 q1 = *(const float4*)&q_s[rt+16][d];
      a00 += q0.x*k0.x + q0.y*k0.y + q0.z*k0.z + q0.w*k0.w;
      a01 += q0.x*k1.x + q0.y*k1.y + q0.z*k1.z + q0.w*k1.w;
      a10 += q1.x*k0.x + q1.y*k0.y + q1.z*k0.z + q1.w*k0.w;
      a11 += q1.x*k1.x + q1.y*k1.y + q1.z*k1.z + q1.w*k1.w;
    }
    s_s[rt   ][kcol  ] = (kcol   < cc) ? expf(a00) : 0.f;
    s_s[rt   ][kcol+1] = (kcol+1 < cc) ? expf(a01) : 0.f;
    s_s[rt+16][kcol  ] = (kcol   < cc) ? expf(a10) : 0.f;
    s_s[rt+16][kcol+1] = (kcol+1 < cc) ? expf(a11) : 0.f;
    __syncthreads();
    // row-sum accumulate (l) while V gather proceeds below
    if (t < 32){
      float s = 0.f;
      #pragma unroll
      for (int c2 = 0; c2 < CK; ++c2) s += s_s[t][c2];
      l_s[t] += s;
    }
    // gather V chunk (overwrites kv_s; QK readers already past barrier)
    #pragma unroll
    for (int it = 0; it < 4; ++it){
      int e = it*256 + t, row = e >> 5, c4 = e & 31;
      int j = (row < cc) ? (int)sel[c0 + row] : 0;
      *(float4*)&kv_s[row][c4*4] = ((const float4*)(V + ((size_t)h*Nn + j)*Dd))[c4];
    }
    __syncthreads();
    // PV: rows {rt, rt+16}, cols d0..d0+7
    for (int c2 = 0; c2 < cc; ++c2){
      float p0 = s_s[rt][c2], p1 = s_s[rt+16][c2];
      float4 va = *(const float4*)&kv_s[c2][d0];
      float4 vb = *(const float4*)&kv_s[c2][d0+4];
      acc2[0][0] += p0*va.x; acc2[0][1] += p0*va.y;
      acc2[0][2] += p0*va.z; acc2[0][3] += p0*va.w;
      acc2[0][4] += p0*vb.x; acc2[0][5] += p0*vb.y;
      acc2[0][6] += p0*vb.z; acc2[0][7] += p0*vb.w;
      acc2[1][0] += p1*va.x; acc2[1][1] += p1*va.y;
      acc2[1][2] += p1*va.z; acc2[1][3] += p1*va.w;
      acc2[1][4] += p1*vb.x; acc2[1][5] += p1*vb.y;
      acc2[1][6] += p1*vb.z; acc2[1][7] += p1*vb.w;
    }
    __syncthreads();
  }

  if (t < 32) l_s[t] = 1.0f / l_s[t];
  __syncthreads();

  #pragma unroll
  for (int rr = 0; rr < 2; ++rr){
    const int r = rr*16 + rt;
    const float il = l_s[r];
    size_t o = ((size_t)h*Nn + (size_t)g*BMq + half*32 + r)*Dd + d0;
    float4 ca = *(const float4*)(OC + o);
    float4 cb = *(const float4*)(OC + o + 4);
    float4 ra, rb;
    ra.x = acc2[rr][0]*il + ca.x; ra.y = acc2[rr][1]*il + ca.y;
    ra.z = acc2[rr][2]*il + ca.z; ra.w = acc2[rr][3]*il + ca.w;
    rb.x = acc2[rr][4]*il + cb.x; rb.y = acc2[rr][5]*il + cb.y;
    rb.z = acc2[rr][6]*il + cb.z; rb.w = acc2[rr][7]*il + cb.w;
    *(float4*)(out + o)     = ra;
    *(float4*)(out + o + 4) = rb;
  }
}

extern "C" void kernel_launch(void* const* d_in, const int* in_sizes, int n_in,
                              void* d_out, int out_size, void* d_ws, size_t ws_size,
                              hipStream_t stream) {
  (void)in_sizes; (void)n_in; (void)out_size; (void)d_ws; (void)ws_size;
  const float* Q  = (const float*)d_in[0];
  const float* K  = (const float*)d_in[1];
  const float* V  = (const float*)d_in[2];
  const float* OC = (const float*)d_in[3];
  float* out = (float*)d_out;
  hipLaunchKernelGGL(k1a_scores, dim3(Hh*16*16),  dim3(256), 0, stream, Q, K);
  hipLaunchKernelGGL(k2_mask,    dim3(Hh*QGg),    dim3(256), 0, stream);
  hipLaunchKernelGGL(k3_attn,    dim3(Hh*QGg*2),  dim3(256), 0, stream, Q, K, V, OC, out);
}

// Round 7
// 546.199 us; speedup vs baseline: 2.8180x; 1.4106x over previous
//
#include <hip/hip_runtime.h>
#include <math.h>

// SparseDiffAttn: B=1,H=12,N=2048,D=128, BM=64, top-k=192, static window [c-153,c+153),
// random keys via modern-JAX randint under jax_threefry_partitionable=True:
//   k1 = tf((0,1),(0,0)), k2 = tf((0,1),(0,1))        [fold-like split]
//   bits(k,i) = b1^b2 with (b1,b2) = tf(k,(0,i))      [partitionable random_bits]
//   offset = ((hi%100)*96 + lo%100) % 100; rnd <=> offset==0
constexpr int Hh   = 12;
constexpr int Nn   = 2048;
constexpr int Dd   = 128;
constexpr int BMq  = 64;
constexpr int QGg  = 32;            // Nn/BMq
constexpr int KSEL = 192;           // 64 * round(0.1*2048/64)
constexpr int CK   = 32;            // key chunk (k3)
constexpr int DC   = 32;            // d-chunk (k1a)
constexpr int LSTR = 132;           // padded LDS row stride (floats)
constexpr float SCALE = 0.08838834764831845f;  // 1/sqrt(128)

// persistent scratch (fully rewritten every launch before any read)
__device__ float          g_E [(size_t)Hh*Nn*Nn];   // 201 MB: exp(score), [h*2048+row][j]
__device__ float          g_lp[(size_t)Hh*Nn*16];   // per-jb partial row sums
__device__ float          g_bs[(size_t)Hh*QGg*Nn];  // colsum scores per group
__device__ unsigned short g_sel[Hh*QGg*Nn];
__device__ int            g_cnt[Hh*QGg];

__device__ __forceinline__ unsigned int rotl32(unsigned int x, int n){
  return (x << n) | (x >> (32 - n));
}

// threefry2x32, 20 rounds, arbitrary key
__device__ __forceinline__ void tf2x32(unsigned int k0, unsigned int k1,
                                       unsigned int x0, unsigned int x1,
                                       unsigned int &o0, unsigned int &o1){
  const unsigned int ks2 = 0x1BD11BDAu ^ k0 ^ k1;
  x0 += k0; x1 += k1;
  x0 += x1; x1 = rotl32(x1,13); x1 ^= x0;
  x0 += x1; x1 = rotl32(x1,15); x1 ^= x0;
  x0 += x1; x1 = rotl32(x1,26); x1 ^= x0;
  x0 += x1; x1 = rotl32(x1, 6); x1 ^= x0;
  x0 += k1; x1 += ks2 + 1u;
  x0 += x1; x1 = rotl32(x1,17); x1 ^= x0;
  x0 += x1; x1 = rotl32(x1,29); x1 ^= x0;
  x0 += x1; x1 = rotl32(x1,16); x1 ^= x0;
  x0 += x1; x1 = rotl32(x1,24); x1 ^= x0;
  x0 += ks2; x1 += k0 + 2u;
  x0 += x1; x1 = rotl32(x1,13); x1 ^= x0;
  x0 += x1; x1 = rotl32(x1,15); x1 ^= x0;
  x0 += x1; x1 = rotl32(x1,26); x1 ^= x0;
  x0 += x1; x1 = rotl32(x1, 6); x1 ^= x0;
  x0 += k0; x1 += k1 + 3u;
  x0 += x1; x1 = rotl32(x1,17); x1 ^= x0;
  x0 += x1; x1 = rotl32(x1,29); x1 ^= x0;
  x0 += x1; x1 = rotl32(x1,16); x1 ^= x0;
  x0 += x1; x1 = rotl32(x1,24); x1 ^= x0;
  x0 += k1; x1 += ks2 + 4u;
  x0 += x1; x1 = rotl32(x1,13); x1 ^= x0;
  x0 += x1; x1 = rotl32(x1,15); x1 ^= x0;
  x0 += x1; x1 = rotl32(x1,26); x1 ^= x0;
  x0 += x1; x1 = rotl32(x1, 6); x1 ^= x0;
  x0 += ks2; x1 += k0 + 5u;
  o0 = x0; o1 = x1;
}

// partitionable-threefry randint(key(1), ..., 0, 100) == 0 for flat element idx
__device__ __forceinline__ bool jax_rand01(unsigned int idx,
                                           unsigned int k1a, unsigned int k1b,
                                           unsigned int k2a, unsigned int k2b){
  unsigned int h0, h1, l0, l1;
  tf2x32(k1a, k1b, 0u, idx, h0, h1);
  tf2x32(k2a, k2b, 0u, idx, l0, l1);
  unsigned int h = h0 ^ h1;
  unsigned int l = l0 ^ l1;
  unsigned int off = ((h % 100u) * 96u + (l % 100u)) % 100u;
  return off == 0u;
}

// ---------------- Kernel 1a: one-pass E=exp(QK^T*scale) + partial row sums ----------------
__global__ __launch_bounds__(256) void k1a_scores(const float* __restrict__ Q,
                                                  const float* __restrict__ K){
  const int bid = blockIdx.x;
  const int jb = bid & 15, gp = (bid >> 4) & 15, h = bid >> 8;
  const int t = threadIdx.x, tx = t & 15, ty = t >> 4;
  __shared__ float Qt[DC][LSTR];   // transposed, pre-scaled
  __shared__ float Kt[DC][LSTR];   // transposed
  __shared__ float lsum[128][17];

  const int R0 = gp*128, J0 = jb*128;
  const float* Qb = Q + ((size_t)h*Nn + R0)*Dd;
  const float* Kb = K + ((size_t)h*Nn + J0)*Dd;

  float acc[8][8] = {};
  float4 qreg[4], kreg[4];
  #pragma unroll
  for (int it = 0; it < 4; ++it){
    int e = it*256 + t, r = e >> 3, d4 = e & 7;
    qreg[it] = ((const float4*)(Qb + (size_t)r*Dd))[d4];
    kreg[it] = ((const float4*)(Kb + (size_t)r*Dd))[d4];
  }
  for (int c = 0; c < Dd/DC; ++c){
    #pragma unroll
    for (int it = 0; it < 4; ++it){
      int e = it*256 + t, r = e >> 3, d4 = e & 7;
      float4 qv = qreg[it], kv = kreg[it];
      Qt[d4*4+0][r] = qv.x*SCALE; Qt[d4*4+1][r] = qv.y*SCALE;
      Qt[d4*4+2][r] = qv.z*SCALE; Qt[d4*4+3][r] = qv.w*SCALE;
      Kt[d4*4+0][r] = kv.x; Kt[d4*4+1][r] = kv.y;
      Kt[d4*4+2][r] = kv.z; Kt[d4*4+3][r] = kv.w;
    }
    __syncthreads();
    if (c < Dd/DC - 1){
      const int d0 = (c+1)*DC;
      #pragma unroll
      for (int it = 0; it < 4; ++it){
        int e = it*256 + t, r = e >> 3, d4 = e & 7;
        qreg[it] = ((const float4*)(Qb + (size_t)r*Dd + d0))[d4];
        kreg[it] = ((const float4*)(Kb + (size_t)r*Dd + d0))[d4];
      }
    }
    #pragma unroll 8
    for (int dd = 0; dd < DC; ++dd){
      float a[8], b[8];
      *(float4*)&a[0] = *(const float4*)&Qt[dd][ty*8];
      *(float4*)&a[4] = *(const float4*)&Qt[dd][ty*8+4];
      *(float4*)&b[0] = *(const float4*)&Kt[dd][tx*8];
      *(float4*)&b[4] = *(const float4*)&Kt[dd][tx*8+4];
      #pragma unroll
      for (int i = 0; i < 8; ++i)
        #pragma unroll
        for (int j = 0; j < 8; ++j)
          acc[i][j] += a[i]*b[j];
    }
    __syncthreads();
  }

  #pragma unroll
  for (int i = 0; i < 8; ++i){
    const int r = ty*8 + i;
    float ev[8]; float s = 0.f;
    #pragma unroll
    for (int j = 0; j < 8; ++j){ ev[j] = expf(acc[i][j]); s += ev[j]; }
    lsum[r][tx] = s;
    float4 e0, e1;
    e0.x=ev[0]; e0.y=ev[1]; e0.z=ev[2]; e0.w=ev[3];
    e1.x=ev[4]; e1.y=ev[5]; e1.z=ev[6]; e1.w=ev[7];
    float* Ep = &g_E[((size_t)h*Nn + R0 + r)*Nn + J0 + tx*8];
    *(float4*)Ep = e0;
    *(float4*)(Ep+4) = e1;
  }
  __syncthreads();
  if (t < 128){
    float s = 0.f;
    #pragma unroll
    for (int x = 0; x < 16; ++x) s += lsum[t][x];
    g_lp[((size_t)h*Nn + R0 + t)*16 + jb] = s;
  }
}

// ---------------- Kernel 2a: parallel weighted colsum bs_j = sum_r E_rj / l_r ----------------
// grid = Hh*QGg*2; block covers 1024 consecutive j (thread -> float4 of j).
__global__ __launch_bounds__(256) void k2a_colsum(){
  const int bid = blockIdx.x;
  const int half = bid & 1, gg = bid >> 1;
  const int h = gg / QGg, g = gg % QGg, t = threadIdx.x;
  __shared__ float il[BMq];
  if (t < BMq){
    const float* lp = &g_lp[((size_t)h*Nn + g*BMq + t)*16];
    float s = 0.f;
    #pragma unroll
    for (int x = 0; x < 16; ++x) s += lp[x];
    il[t] = 1.0f / s;
  }
  __syncthreads();
  const int j0 = half*1024 + t*4;
  const float* Ep = &g_E[((size_t)h*Nn + (size_t)g*BMq)*Nn + j0];
  float4 s = {0.f, 0.f, 0.f, 0.f};
  #pragma unroll 4
  for (int r = 0; r < BMq; r += 2){
    float4 e0 = *(const float4*)(Ep + (size_t)r*Nn);
    float4 e1 = *(const float4*)(Ep + (size_t)(r+1)*Nn);
    float w0 = il[r], w1 = il[r+1];
    s.x += e0.x*w0 + e1.x*w1;
    s.y += e0.y*w0 + e1.y*w1;
    s.z += e0.z*w0 + e1.z*w1;
    s.w += e0.w*w0 + e1.w*w1;
  }
  *(float4*)&g_bs[(size_t)gg*Nn + j0] = s;
}

// ---------------- Kernel 2b: top-k + random + static window -> compacted key list ----------------
__global__ __launch_bounds__(256) void k2b_mask(){
  const int bid = blockIdx.x, g = bid % QGg, t = threadIdx.x;
  __shared__ float bsv[Nn];
  __shared__ int red;
  __shared__ int csel;
  const float* src = g_bs + (size_t)bid*Nn;
  #pragma unroll
  for (int it = 0; it < 2; ++it)
    *(float4*)&bsv[(it*256 + t)*4] = *(const float4*)&src[(it*256 + t)*4];
  if (t == 0){ red = 0; csel = 0; }
  __syncthreads();

  unsigned int k1a, k1b, k2a, k2b;
  tf2x32(0u, 1u, 0u, 0u, k1a, k1b);
  tf2x32(0u, 1u, 0u, 1u, k2a, k2b);

  // 192nd-largest value via bitwise binary search (values positive -> uint order)
  unsigned int prefix = 0u;
  for (int bit = 31; bit >= 0; --bit){
    unsigned int cand = prefix | (1u << bit);
    int c = 0;
    #pragma unroll
    for (int it = 0; it < 8; ++it)
      c += (__float_as_uint(bsv[it*256 + t]) >= cand) ? 1 : 0;
    #pragma unroll
    for (int off = 32; off > 0; off >>= 1) c += __shfl_down(c, off);
    if ((t & 63) == 0) atomicAdd(&red, c);
    __syncthreads();
    int total = red;
    __syncthreads();
    if (t == 0) red = 0;
    __syncthreads();
    if (total >= KSEL) prefix = cand;
  }
  {
    int cg = 0;
    #pragma unroll
    for (int it = 0; it < 8; ++it)
      cg += (__float_as_uint(bsv[it*256 + t]) > prefix) ? 1 : 0;
    #pragma unroll
    for (int off = 32; off > 0; off >>= 1) cg += __shfl_down(cg, off);
    if ((t & 63) == 0) atomicAdd(&red, cg);
  }
  __syncthreads();
  const int need = KSEL - red;   // ties taken lowest-index-first (jax top_k)

  const int lo = g*BMq + BMq/2 - 153;   // ws=int(0.15*2048)=307, ws//2=153
  const int hi = g*BMq + BMq/2 + 153;
  const int ssum = ((hi < Nn) ? hi : Nn) - ((lo > 0) ? lo : 0);
  const bool vqg = (ssum + KSEL) < Nn;  // always true at this config

  for (int it = 0; it < 8; ++it){
    int j = it*256 + t;
    unsigned int bu = __float_as_uint(bsv[j]);
    bool topk = bu > prefix;
    if (!topk && bu == prefix){
      int tr = 0;
      for (int jj = 0; jj < j; ++jj)
        tr += (__float_as_uint(bsv[jj]) == prefix) ? 1 : 0;
      topk = (tr < need);
    }
    bool rnd = jax_rand01((unsigned)(bid*Nn + j), k1a, k1b, k2a, k2b);
    bool st  = (j >= lo) && (j < hi);
    bool selb = st || ((rnd || topk) && vqg);
    if (selb){
      int slot = atomicAdd(&csel, 1);
      g_sel[(size_t)bid*Nn + slot] = (unsigned short)j;
    }
  }
  __syncthreads();
  if (t == 0) g_cnt[bid] = csel;
}

// ---------------- Kernel 3: ONE-PASS masked attention (no-max exp trick) ----------------
// Block = 32 query rows (half of a group) x all selected keys. Grid = H*QG*2 = 768.
__global__ __launch_bounds__(256) void k3_attn(const float* __restrict__ Q,
                                               const float* __restrict__ K,
                                               const float* __restrict__ V,
                                               const float* __restrict__ OC,
                                               float* __restrict__ out){
  const int bid = blockIdx.x;
  const int half = bid & 1;
  const int gg   = bid >> 1;           // h*QGg + g
  const int h = gg / QGg, g = gg % QGg;
  const int t = threadIdx.x;
  __shared__ float q_s[32][Dd+4];
  __shared__ float kv_s[CK][Dd+4];
  __shared__ float s_s[32][CK+1];
  __shared__ float l_s[32];
  const int c = g_cnt[gg];
  const unsigned short* sel = g_sel + (size_t)gg*Nn;

  const float* qb = Q + ((size_t)h*Nn + (size_t)g*BMq + half*32)*Dd;
  #pragma unroll
  for (int it = 0; it < 4; ++it){
    int e = it*256 + t;                 // 1024 float4s = 32 rows x 32 f4
    int row = e >> 5, c4 = e & 31;
    float4 vq = ((const float4*)qb)[e];
    float4 sv; sv.x = vq.x*SCALE; sv.y = vq.y*SCALE; sv.z = vq.z*SCALE; sv.w = vq.w*SCALE;
    *(float4*)&q_s[row][c4*4] = sv;
  }
  if (t < 32) l_s[t] = 0.0f;
  __syncthreads();

  const int rt = t & 15, kt = t >> 4, kcol = kt*2;
  const int d0 = (t >> 4)*8;           // PV column group
  float acc2[2][8] = {};

  for (int c0 = 0; c0 < c; c0 += CK){
    const int cc = ((c - c0) < CK) ? (c - c0) : CK;
    // gather K chunk
    #pragma unroll
    for (int it = 0; it < 4; ++it){
      int e = it*256 + t, row = e >> 5, c4 = e & 31;
      int j = (row < cc) ? (int)sel[c0 + row] : 0;
      *(float4*)&kv_s[row][c4*4] = ((const float4*)(K + ((size_t)h*Nn + j)*Dd))[c4];
    }
    __syncthreads();
    // scores: rows {rt, rt+16} x cols {kcol, kcol+1}
    float a00=0.f, a01=0.f, a10=0.f, a11=0.f;
    #pragma unroll 8
    for (int d = 0; d < Dd; d += 4){
      float4 k0 = *(const float4*)&kv_s[kcol][d];
      float4 k1 = *(const float4*)&kv_s[kcol+1][d];
      float4 q0 = *(const float4*)&q_s[rt][d];
      float4 q1 = *(const float4*)&q_s[rt+16][d];
      a00 += q0.x*k0.x + q0.y*k0.y + q0.z*k0.z + q0.w*k0.w;
      a01 += q0.x*k1.x + q0.y*k1.y + q0.z*k1.z + q0.w*k1.w;
      a10 += q1.x*k0.x + q1.y*k0.y + q1.z*k0.z + q1.w*k0.w;
      a11 += q1.x*k1.x + q1.y*k1.y + q1.z*k1.z + q1.w*k1.w;
    }
    s_s[rt   ][kcol  ] = (kcol   < cc) ? expf(a00) : 0.f;
    s_s[rt   ][kcol+1] = (kcol+1 < cc) ? expf(a01) : 0.f;
    s_s[rt+16][kcol  ] = (kcol   < cc) ? expf(a10) : 0.f;
    s_s[rt+16][kcol+1] = (kcol+1 < cc) ? expf(a11) : 0.f;
    __syncthreads();
    // row-sum accumulate (l)
    if (t < 32){
      float s = 0.f;
      #pragma unroll
      for (int c2 = 0; c2 < CK; ++c2) s += s_s[t][c2];
      l_s[t] += s;
    }
    // gather V chunk (overwrites kv_s; QK readers already past barrier)
    #pragma unroll
    for (int it = 0; it < 4; ++it){
      int e = it*256 + t, row = e >> 5, c4 = e & 31;
      int j = (row < cc) ? (int)sel[c0 + row] : 0;
      *(float4*)&kv_s[row][c4*4] = ((const float4*)(V + ((size_t)h*Nn + j)*Dd))[c4];
    }
    __syncthreads();
    // PV: rows {rt, rt+16}, cols d0..d0+7
    for (int c2 = 0; c2 < cc; ++c2){
      float p0 = s_s[rt][c2], p1 = s_s[rt+16][c2];
      float4 va = *(const float4*)&kv_s[c2][d0];
      float4 vb = *(const float4*)&kv_s[c2][d0+4];
      acc2[0][0] += p0*va.x; acc2[0][1] += p0*va.y;
      acc2[0][2] += p0*va.z; acc2[0][3] += p0*va.w;
      acc2[0][4] += p0*vb.x; acc2[0][5] += p0*vb.y;
      acc2[0][6] += p0*vb.z; acc2[0][7] += p0*vb.w;
      acc2[1][0] += p1*va.x; acc2[1][1] += p1*va.y;
      acc2[1][2] += p1*va.z; acc2[1][3] += p1*va.w;
      acc2[1][4] += p1*vb.x; acc2[1][5] += p1*vb.y;
      acc2[1][6] += p1*vb.z; acc2[1][7] += p1*vb.w;
    }
    __syncthreads();
  }

  if (t < 32) l_s[t] = 1.0f / l_s[t];
  __syncthreads();

  #pragma unroll
  for (int rr = 0; rr < 2; ++rr){
    const int r = rr*16 + rt;
    const float il = l_s[r];
    size_t o = ((size_t)h*Nn + (size_t)g*BMq + half*32 + r)*Dd + d0;
    float4 ca = *(const float4*)(OC + o);
    float4 cb = *(const float4*)(OC + o + 4);
    float4 ra, rb;
    ra.x = acc2[rr][0]*il + ca.x; ra.y = acc2[rr][1]*il + ca.y;
    ra.z = acc2[rr][2]*il + ca.z; ra.w = acc2[rr][3]*il + ca.w;
    rb.x = acc2[rr][4]*il + cb.x; rb.y = acc2[rr][5]*il + cb.y;
    rb.z = acc2[rr][6]*il + cb.z; rb.w = acc2[rr][7]*il + cb.w;
    *(float4*)(out + o)     = ra;
    *(float4*)(out + o + 4) = rb;
  }
}

extern "C" void kernel_launch(void* const* d_in, const int* in_sizes, int n_in,
                              void* d_out, int out_size, void* d_ws, size_t ws_size,
                              hipStream_t stream) {
  (void)in_sizes; (void)n_in; (void)out_size; (void)d_ws; (void)ws_size;
  const float* Q  = (const float*)d_in[0];
  const float* K  = (const float*)d_in[1];
  const float* V  = (const float*)d_in[2];
  const float* OC = (const float*)d_in[3];
  float* out = (float*)d_out;
  hipLaunchKernelGGL(k1a_scores, dim3(Hh*16*16), dim3(256), 0, stream, Q, K);
  hipLaunchKernelGGL(k2a_colsum, dim3(Hh*QGg*2), dim3(256), 0, stream);
  hipLaunchKernelGGL(k2b_mask,   dim3(Hh*QGg),   dim3(256), 0, stream);
  hipLaunchKernelGGL(k3_attn,    dim3(Hh*QGg*2), dim3(256), 0, stream, Q, K, V, OC, out);
}